// Round 16
// baseline (265.023 us; speedup 1.0000x reference)
//
#include <hip/hip_runtime.h>

#define TOK 2048
#define DDIM 1024
#define HDIM 1408
#define ENUM 8
#define NSLOT (2 * TOK)
#define UP_NB 22   // HDIM / 64
#define UP_KS 32   // DDIM / 32
#define DN_NB 16   // DDIM / 64
#define DN_KS 44   // HDIM / 32
#define DN_KH 22   // DN_KS / 2 (K-split halves)
#define TC_W1_BLK 2816   // 16 z * 22 nb * 8 ksg
#define TC_ALL_BLK 4224  // + 8 e * 16 nb * 11 ksg
#define GATE_BLK 512     // 2048 tokens / 4 per block; dispatched FIRST

typedef unsigned int uint;
typedef unsigned short ushort;
typedef unsigned long long ull;

using bf16x8 = __attribute__((ext_vector_type(8))) __bf16;
using f32x4  = __attribute__((ext_vector_type(4))) float;

__device__ __forceinline__ float silu_f(float g) {
    return g / (1.0f + __expf(-g));
}

__device__ __forceinline__ ushort cvt_bf16(float f) {
    uint u = __float_as_uint(f);
    u += 0x7FFFu + ((u >> 16) & 1u);   // RNE
    return (ushort)(u >> 16);
}

// async global->LDS: per-lane global address, LDS dest = wave-uniform base + lane*16
__device__ __forceinline__ void gl2lds16(const void* g, void* l) {
    __builtin_amdgcn_global_load_lds(
        (const __attribute__((address_space(1))) uint*)g,
        (__attribute__((address_space(3))) uint*)l, 16, 0, 0);
}

// ---- inline gate2: deterministic ballot-scan of tinfo. Each token maps to
//      at most ONE slot per expert (i0 != i1), so expert-e's list in token
//      order is a prefix-sum. Builds rowslot[0..127] for rows [m0, m0+128),
//      returns cnt. No atomics, no fences — tinfo ordered by kernel bound. -
__device__ __forceinline__ int build_rowslot(
    const int* __restrict__ tinfo, int e, int m0, int tid, int lane, int w,
    int* rowslot, int* wcnt)
{
    if (tid < 128) rowslot[tid] = -1;
    int base = 0;
    for (int t0 = 0; t0 < TOK; t0 += 256) {
        const int t = t0 + tid;
        const int info = tinfo[t];
        const int c1 = ((info >> 4) == e);
        const int flag = ((info & 15) == e) | c1;
        const ull m = __ballot(flag != 0);
        if (lane == 0) wcnt[w] = __popcll(m);
        __syncthreads();
        int wbase = base;
#pragma unroll
        for (int i = 0; i < 4; ++i) wbase += (i < w) ? wcnt[i] : 0;
        base += wcnt[0] + wcnt[1] + wcnt[2] + wcnt[3];
        if (flag) {
            int idx = wbase + __popcll(m & ((1ull << lane) - 1)) - m0;
            if (idx >= 0 && idx < 128)
                rowslot[idx] = (t << 1) | c1;
        }
        __syncthreads();   // protect wcnt before next overwrite
    }
    return base;
}

// ---- kernel 1 (r13 exact): gate1 blocks first, then weight precast -------
__global__ __launch_bounds__(256) void tcast_gate_kernel(
    const float* __restrict__ w1g, const float* __restrict__ w1u,
    const float* __restrict__ w2, ushort* __restrict__ BgP,
    ushort* __restrict__ BuP, ushort* __restrict__ W2P,
    const float* __restrict__ x, const float* __restrict__ gw,
    int* __restrict__ tinfo, float* __restrict__ wslot, ushort* __restrict__ xb)
{
    const int bid = blockIdx.x;
    const int tid = threadIdx.x;

    if (bid >= GATE_BLK) {
        // ---- weight cast: 4 ks-tiles per block, no LDS (r5 exact) ----
        const int cb = bid - GATE_BLK;
        const float* src; ushort* dst; int N, KS, NB, e, nb, ks0;
        if (cb < TC_W1_BLK) {
            const int z = cb / 176;             // 176 = 22 nb * 8 ksg
            const int rem = cb - z * 176;
            src = (z & 8) ? w1u : w1g;
            dst = (z & 8) ? BuP : BgP;
            N = HDIM; KS = UP_KS; NB = UP_NB; e = z & 7;
            nb = rem >> 3; ks0 = (rem & 7) * 4;
        } else {
            const int b2 = cb - TC_W1_BLK;
            e = b2 / 176;                       // 176 = 16 nb * 11 ksg
            const int rem = b2 - e * 176;
            src = w2; dst = W2P;
            N = DDIM; KS = DN_KS; NB = DN_NB;
            nb = rem / 11; ks0 = (rem - nb * 11) * 4;
        }
        const int kg = tid & 3;
        const int nn = tid >> 2;
        const float* sb = src + (size_t)e * ((size_t)KS * 32) * N + nb * 64 + nn;
        ushort* db = dst + ((((size_t)e * NB + nb) * KS) + ks0) * 2048 + nn * 32 + kg * 8;
#pragma unroll
        for (int ksi = 0; ksi < 4; ++ksi) {
            const float* st = sb + (size_t)((ks0 + ksi) * 32 + kg * 8) * N;
            float v[8];
#pragma unroll
            for (int j = 0; j < 8; ++j) v[j] = st[(size_t)j * N];
            ushort o[8];
#pragma unroll
            for (int j = 0; j < 8; ++j) o[j] = cvt_bf16(v[j]);
            *(uint4*)(db + ksi * 2048) = *(uint4*)o;
        }
        return;
    }

    // ---- gate1: 4 tokens per block, one wave each (r5 exact body) ----
    const int t = bid * 4 + (tid >> 6);
    const int lane = tid & 63;
    const float* xr = x + (size_t)t * DDIM;
    ushort* xbr = xb + (size_t)t * DDIM;
    float xv[16];
#pragma unroll
    for (int i = 0; i < 16; ++i) xv[i] = xr[lane + 64 * i];
#pragma unroll
    for (int i = 0; i < 16; ++i) xbr[lane + 64 * i] = cvt_bf16(xv[i]);
    float logit[ENUM];
#pragma unroll
    for (int e = 0; e < ENUM; ++e) {
        const float* gr = gw + (size_t)e * DDIM;
        float acc = 0.f;
#pragma unroll
        for (int i = 0; i < 16; ++i) acc += xv[i] * gr[lane + 64 * i];
#pragma unroll
        for (int s = 32; s > 0; s >>= 1) acc += __shfl_xor(acc, s, 64);
        logit[e] = acc;
    }
    if (lane == 0) {
        float mx = logit[0];
#pragma unroll
        for (int e = 1; e < ENUM; ++e) mx = fmaxf(mx, logit[e]);
        float p[ENUM]; float se = 0.f;
#pragma unroll
        for (int e = 0; e < ENUM; ++e) { p[e] = __expf(logit[e] - mx); se += p[e]; }
        float inv = 1.0f / se;
#pragma unroll
        for (int e = 0; e < ENUM; ++e) p[e] *= inv;
        int i0 = 0;
#pragma unroll
        for (int e = 1; e < ENUM; ++e) if (p[e] > p[i0]) i0 = e;
        int i1 = (i0 == 0) ? 1 : 0;
#pragma unroll
        for (int e = 0; e < ENUM; ++e) if (e != i0 && p[e] > p[i1]) i1 = e;
        tinfo[t] = i0 | (i1 << 4);
        wslot[(t << 1)] = p[i0];
        wslot[(t << 1) | 1] = p[i1];
    }
}

// ---- up: Hbuf[slot] = silu(x@w1g[e]) * (x@w1u[e]); TM=128 TN=64, dbuf,
//      4 waves 2x2, XOR-swizzled LDS; rowslot built in-block (no gate2) ----
__global__ __launch_bounds__(256, 4) void up_mfma(
    const ushort* __restrict__ xb, const ushort* __restrict__ BgP,
    const ushort* __restrict__ BuP, const int* __restrict__ tinfo,
    ushort* __restrict__ Hbuf)
{
    const int e = blockIdx.z;
    const int m0 = blockIdx.y * 128;
    const int nb = blockIdx.x;
    const int tid = threadIdx.x;
    const int w = tid >> 6;
    const int lane = tid & 63;
    const int q = lane >> 4;
    const int l15 = lane & 15;
    const int wr = w >> 1;   // 0..1 : m half (64 rows)
    const int wc = w & 1;    // 0..1 : n half (32 cols)

    __shared__ ushort As[2][128][32];
    __shared__ ushort Bgs[2][64][32];
    __shared__ ushort Bus[2][64][32];
    __shared__ int rowslot[128];
    __shared__ int wcnt[4];

    const int cnt = build_rowslot(tinfo, e, m0, tid, lane, w, rowslot, wcnt);
    if (m0 >= cnt) return;

    const int srow = w * 16 + (lane >> 2);
    const int clog = (((lane & 3) + 4 - ((srow >> 1) & 3)) & 3) * 8;
    const int as0 = rowslot[srow];
    const int as1 = rowslot[srow + 64];
    const ushort* agp0 = xb + (size_t)(as0 < 0 ? 0 : (as0 >> 1)) * DDIM + clog;
    const ushort* agp1 = xb + (size_t)(as1 < 0 ? 0 : (as1 >> 1)) * DDIM + clog;
    const size_t tb = (size_t)(e * UP_NB + nb) * UP_KS * 2048;
    const ushort* bgp = BgP + tb + srow * 32 + clog;
    const ushort* bup = BuP + tb + srow * 32 + clog;

    const int coff = ((q + (l15 >> 1)) & 3) * 8;

    f32x4 accg[4][2], accu[4][2];
#pragma unroll
    for (int i = 0; i < 4; ++i)
#pragma unroll
        for (int j = 0; j < 2; ++j) { accg[i][j] = (f32x4)0.f; accu[i][j] = (f32x4)0.f; }

#define UP_PREFETCH(KSV, B)                                        \
    {                                                              \
        gl2lds16(agp0 + (KSV) * 32, &As[B][w * 16][0]);            \
        gl2lds16(agp1 + (KSV) * 32, &As[B][64 + w * 16][0]);       \
        gl2lds16(bgp + (size_t)(KSV) * 2048, &Bgs[B][w * 16][0]);  \
        gl2lds16(bup + (size_t)(KSV) * 2048, &Bus[B][w * 16][0]);  \
    }

    UP_PREFETCH(0, 0);
    __syncthreads();

    for (int ks = 0; ks < UP_KS; ++ks) {
        const int cur = ks & 1;
        const int nxt = cur ^ 1;
        if (ks + 1 < UP_KS) UP_PREFETCH(ks + 1, nxt);

        bf16x8 a[4], bg[2], bu[2];
#pragma unroll
        for (int mi = 0; mi < 4; ++mi)
            a[mi] = *(const bf16x8*)&As[cur][wr * 64 + mi * 16 + l15][coff];
#pragma unroll
        for (int ni = 0; ni < 2; ++ni) {
            bg[ni] = *(const bf16x8*)&Bgs[cur][wc * 32 + ni * 16 + l15][coff];
            bu[ni] = *(const bf16x8*)&Bus[cur][wc * 32 + ni * 16 + l15][coff];
        }
#pragma unroll
        for (int mi = 0; mi < 4; ++mi)
#pragma unroll
            for (int ni = 0; ni < 2; ++ni) {
                accg[mi][ni] = __builtin_amdgcn_mfma_f32_16x16x32_bf16(a[mi], bg[ni], accg[mi][ni], 0, 0, 0);
                accu[mi][ni] = __builtin_amdgcn_mfma_f32_16x16x32_bf16(a[mi], bu[ni], accu[mi][ni], 0, 0, 0);
            }
        __syncthreads();   // drains prefetch vmem + protects buffer swap
    }
#undef UP_PREFETCH

#pragma unroll
    for (int mi = 0; mi < 4; ++mi) {
#pragma unroll
        for (int r = 0; r < 4; ++r) {
            int ml = wr * 64 + mi * 16 + q * 4 + r;
            int slot = rowslot[ml];
            if (slot < 0) continue;
            ushort* hrow = Hbuf + (size_t)slot * HDIM + nb * 64 + wc * 32 + l15;
#pragma unroll
            for (int ni = 0; ni < 2; ++ni)
                hrow[ni * 16] = cvt_bf16(silu_f(accg[mi][ni][r]) * accu[mi][ni][r]);
        }
    }
}

// ---- down: Ybuf partials = Hbuf[slot] @ w2[e]; TM=128 TN=128, K-split 2,
//      dbuf, swizzled; rowslot built in-block (no gate2) -------------------
__global__ __launch_bounds__(256, 4) void down_mfma(
    const ushort* __restrict__ Hbuf, const ushort* __restrict__ W2P,
    const int* __restrict__ tinfo, float* __restrict__ Ybuf)
{
    const int z = blockIdx.z;           // 0..15: expert*2 + K-half
    const int e = z >> 1;
    const int kh = z & 1;
    const int m0 = blockIdx.y * 128;
    const int nb = blockIdx.x;          // 0..7, 128-wide N blocks
    const int tid = threadIdx.x;
    const int w = tid >> 6;
    const int lane = tid & 63;
    const int q = lane >> 4;
    const int l15 = lane & 15;
    const int wr = w >> 1;
    const int wc = w & 1;

    __shared__ ushort As[2][128][32];
    __shared__ ushort Bs[2][128][32];
    __shared__ int rowslot[128];
    __shared__ int wcnt[4];

    const int cnt = build_rowslot(tinfo, e, m0, tid, lane, w, rowslot, wcnt);
    if (m0 >= cnt) return;

    const int srow = w * 16 + (lane >> 2);
    const int clog = (((lane & 3) + 4 - ((srow >> 1) & 3)) & 3) * 8;
    const int as0 = rowslot[srow];
    const int as1 = rowslot[srow + 64];
    const ushort* agp0 = Hbuf + (size_t)(as0 < 0 ? 0 : as0) * HDIM + kh * (DN_KH * 32) + clog;
    const ushort* agp1 = Hbuf + (size_t)(as1 < 0 ? 0 : as1) * HDIM + kh * (DN_KH * 32) + clog;
    const int nb2 = nb * 2;
    const ushort* bp0 = W2P + ((size_t)(e * DN_NB + nb2) * DN_KS + kh * DN_KH) * 2048 + srow * 32 + clog;
    const ushort* bp1 = W2P + ((size_t)(e * DN_NB + nb2 + 1) * DN_KS + kh * DN_KH) * 2048 + srow * 32 + clog;

    const int coff = ((q + (l15 >> 1)) & 3) * 8;

    f32x4 acc[4][4];
#pragma unroll
    for (int i = 0; i < 4; ++i)
#pragma unroll
        for (int j = 0; j < 4; ++j) acc[i][j] = (f32x4)0.f;

#define DN_PREFETCH(KSV, B)                                           \
    {                                                                 \
        gl2lds16(agp0 + (KSV) * 32, &As[B][w * 16][0]);               \
        gl2lds16(agp1 + (KSV) * 32, &As[B][64 + w * 16][0]);          \
        gl2lds16(bp0 + (size_t)(KSV) * 2048, &Bs[B][w * 16][0]);      \
        gl2lds16(bp1 + (size_t)(KSV) * 2048, &Bs[B][64 + w * 16][0]); \
    }

    DN_PREFETCH(0, 0);
    __syncthreads();

    for (int ks = 0; ks < DN_KH; ++ks) {
        const int cur = ks & 1;
        const int nxt = cur ^ 1;
        if (ks + 1 < DN_KH) DN_PREFETCH(ks + 1, nxt);

        bf16x8 a[4], b[4];
#pragma unroll
        for (int mi = 0; mi < 4; ++mi)
            a[mi] = *(const bf16x8*)&As[cur][wr * 64 + mi * 16 + l15][coff];
#pragma unroll
        for (int ni = 0; ni < 4; ++ni)
            b[ni] = *(const bf16x8*)&Bs[cur][wc * 64 + ni * 16 + l15][coff];
#pragma unroll
        for (int mi = 0; mi < 4; ++mi)
#pragma unroll
            for (int ni = 0; ni < 4; ++ni)
                acc[mi][ni] = __builtin_amdgcn_mfma_f32_16x16x32_bf16(a[mi], b[ni], acc[mi][ni], 0, 0, 0);
        __syncthreads();
    }
#undef DN_PREFETCH

    float* Yp = Ybuf + (size_t)kh * NSLOT * DDIM;
#pragma unroll
    for (int mi = 0; mi < 4; ++mi) {
#pragma unroll
        for (int r = 0; r < 4; ++r) {
            int ml = wr * 64 + mi * 16 + q * 4 + r;
            int slot = rowslot[ml];
            if (slot < 0) continue;
            float* yr = Yp + (size_t)slot * DDIM + nb * 128 + wc * 64 + l15;
#pragma unroll
            for (int ni = 0; ni < 4; ++ni)
                yr[ni * 16] = acc[mi][ni][r];
        }
    }
}

// ---- combine: y[t] = w0*(Y0[2t]+Y1[2t]) + w1*(Y0[2t+1]+Y1[2t+1]) ---------
__global__ __launch_bounds__(256) void combine_kernel(
    const float* __restrict__ Ybuf, const float* __restrict__ wslot,
    float* __restrict__ y)
{
    const int t = blockIdx.x;
    const int j = threadIdx.x * 4;
    const float w0 = wslot[2 * t];
    const float w1 = wslot[2 * t + 1];
    const float* y00 = Ybuf + ((size_t)2 * t) * DDIM + j;
    const float* y01 = Ybuf + ((size_t)2 * t + 1) * DDIM + j;
    const float* y10 = y00 + (size_t)NSLOT * DDIM;
    const float* y11 = y01 + (size_t)NSLOT * DDIM;
    float4 a0 = *(const float4*)y00;
    float4 b0 = *(const float4*)y01;
    float4 a1 = *(const float4*)y10;
    float4 b1 = *(const float4*)y11;
    float4 o;
    o.x = w0 * (a0.x + a1.x) + w1 * (b0.x + b1.x);
    o.y = w0 * (a0.y + a1.y) + w1 * (b0.y + b1.y);
    o.z = w0 * (a0.z + a1.z) + w1 * (b0.z + b1.z);
    o.w = w0 * (a0.w + a1.w) + w1 * (b0.w + b1.w);
    *(float4*)(y + (size_t)t * DDIM + j) = o;
}

extern "C" void kernel_launch(void* const* d_in, const int* in_sizes, int n_in,
                              void* d_out, int out_size, void* d_ws, size_t ws_size,
                              hipStream_t stream) {
    const float* x   = (const float*)d_in[0];
    const float* gw  = (const float*)d_in[1];
    const float* w1g = (const float*)d_in[2];
    const float* w1u = (const float*)d_in[3];
    const float* w2  = (const float*)d_in[4];
    float* y = (float*)d_out;
    char* ws = (char*)d_ws;

    // workspace layout (Ybuf [2 K-halves] aliases BgP/BuP region — dead after up)
    size_t off = 0;
    float*  wslot  = (float*)(ws + off); off += (size_t)NSLOT * 4;        // 16 KB
    int*    tinfo  = (int*)(ws + off);   off += (size_t)TOK * 4;          // 8 KB
    off = (off + 255) & ~(size_t)255;
    ushort* xb     = (ushort*)(ws + off); off += (size_t)TOK * DDIM * 2;  // 4 MB
    size_t regA = off;                                                    // 46 MB region
    ushort* BgP  = (ushort*)(ws + regA);
    ushort* BuP  = (ushort*)(ws + regA + (size_t)ENUM * DDIM * HDIM * 2);
    float*  Ybuf = (float*)(ws + regA);                                   // 33.6 MB alias
    off = regA + (size_t)2 * ENUM * DDIM * HDIM * 2;
    ushort* W2P  = (ushort*)(ws + off);  off += (size_t)ENUM * HDIM * DDIM * 2; // 23 MB
    ushort* Hbuf = (ushort*)(ws + off);                                         // 11.5 MB

    tcast_gate_kernel<<<TC_ALL_BLK + GATE_BLK, 256, 0, stream>>>(
        w1g, w1u, w2, BgP, BuP, W2P, x, gw, tinfo, wslot, xb);

    up_mfma<<<dim3(UP_NB, TOK / 128, ENUM), 256, 0, stream>>>(xb, BgP, BuP, tinfo, Hbuf);
    down_mfma<<<dim3(DDIM / 128, TOK / 128, 16), 256, 0, stream>>>(Hbuf, W2P, tinfo, Ybuf);
    combine_kernel<<<TOK, 256, 0, stream>>>(Ybuf, wslot, y);
}

// Round 17
// 254.597 us; speedup vs baseline: 1.0410x; 1.0410x over previous
//
#include <hip/hip_runtime.h>

#define TOK 2048
#define DDIM 1024
#define HDIM 1408
#define ENUM 8
#define NSLOT (2 * TOK)
#define UP_NB 22   // HDIM / 64
#define UP_KS 32   // DDIM / 32
#define DN_NB 16   // DDIM / 64
#define DN_KS 44   // HDIM / 32
#define DN_KH 22   // DN_KS / 2 (K-split halves)
#define TC_W1_BLK 2816   // 16 z * 22 nb * 8 ksg
#define TC_ALL_BLK 4224  // + 8 e * 16 nb * 11 ksg
#define GATE_BLK 512     // 2048 tokens / 4 per block; dispatched FIRST

typedef unsigned int uint;
typedef unsigned short ushort;
typedef unsigned long long ull;

using bf16x8 = __attribute__((ext_vector_type(8))) __bf16;
using f32x4  = __attribute__((ext_vector_type(4))) float;

__device__ __forceinline__ float silu_f(float g) {
    return g / (1.0f + __expf(-g));
}

__device__ __forceinline__ ushort cvt_bf16(float f) {
    uint u = __float_as_uint(f);
    u += 0x7FFFu + ((u >> 16) & 1u);   // RNE
    return (ushort)(u >> 16);
}

// async global->LDS: per-lane global address, LDS dest = wave-uniform base + lane*16
__device__ __forceinline__ void gl2lds16(const void* g, void* l) {
    __builtin_amdgcn_global_load_lds(
        (const __attribute__((address_space(1))) uint*)g,
        (__attribute__((address_space(3))) uint*)l, 16, 0, 0);
}

// ---- kernel 1 (round-5 bodies, gate-first dispatch): gate1 blocks first
//      (VALU-bound, overlap with cast's memory stalls), then weight precast
//      (LDS-free strided-read transpose) ----------------------------------
__global__ __launch_bounds__(256) void tcast_gate_kernel(
    const float* __restrict__ w1g, const float* __restrict__ w1u,
    const float* __restrict__ w2, ushort* __restrict__ BgP,
    ushort* __restrict__ BuP, ushort* __restrict__ W2P,
    const float* __restrict__ x, const float* __restrict__ gw,
    int* __restrict__ tinfo, float* __restrict__ wslot, ushort* __restrict__ xb)
{
    const int bid = blockIdx.x;
    const int tid = threadIdx.x;

    if (bid >= GATE_BLK) {
        // ---- weight cast: 4 ks-tiles per block, no LDS (r5 exact) ----
        const int cb = bid - GATE_BLK;
        const float* src; ushort* dst; int N, KS, NB, e, nb, ks0;
        if (cb < TC_W1_BLK) {
            const int z = cb / 176;             // 176 = 22 nb * 8 ksg
            const int rem = cb - z * 176;
            src = (z & 8) ? w1u : w1g;
            dst = (z & 8) ? BuP : BgP;
            N = HDIM; KS = UP_KS; NB = UP_NB; e = z & 7;
            nb = rem >> 3; ks0 = (rem & 7) * 4;
        } else {
            const int b2 = cb - TC_W1_BLK;
            e = b2 / 176;                       // 176 = 16 nb * 11 ksg
            const int rem = b2 - e * 176;
            src = w2; dst = W2P;
            N = DDIM; KS = DN_KS; NB = DN_NB;
            nb = rem / 11; ks0 = (rem - nb * 11) * 4;
        }
        const int kg = tid & 3;
        const int nn = tid >> 2;
        const float* sb = src + (size_t)e * ((size_t)KS * 32) * N + nb * 64 + nn;
        ushort* db = dst + ((((size_t)e * NB + nb) * KS) + ks0) * 2048 + nn * 32 + kg * 8;
#pragma unroll
        for (int ksi = 0; ksi < 4; ++ksi) {
            const float* st = sb + (size_t)((ks0 + ksi) * 32 + kg * 8) * N;
            float v[8];
#pragma unroll
            for (int j = 0; j < 8; ++j) v[j] = st[(size_t)j * N];
            ushort o[8];
#pragma unroll
            for (int j = 0; j < 8; ++j) o[j] = cvt_bf16(v[j]);
            *(uint4*)(db + ksi * 2048) = *(uint4*)o;
        }
        return;
    }

    // ---- gate1: 4 tokens per block, one wave each (r5 exact body) ----
    const int t = bid * 4 + (tid >> 6);
    const int lane = tid & 63;
    const float* xr = x + (size_t)t * DDIM;
    ushort* xbr = xb + (size_t)t * DDIM;
    float xv[16];
#pragma unroll
    for (int i = 0; i < 16; ++i) xv[i] = xr[lane + 64 * i];
#pragma unroll
    for (int i = 0; i < 16; ++i) xbr[lane + 64 * i] = cvt_bf16(xv[i]);
    float logit[ENUM];
#pragma unroll
    for (int e = 0; e < ENUM; ++e) {
        const float* gr = gw + (size_t)e * DDIM;
        float acc = 0.f;
#pragma unroll
        for (int i = 0; i < 16; ++i) acc += xv[i] * gr[lane + 64 * i];
#pragma unroll
        for (int s = 32; s > 0; s >>= 1) acc += __shfl_xor(acc, s, 64);
        logit[e] = acc;
    }
    if (lane == 0) {
        float mx = logit[0];
#pragma unroll
        for (int e = 1; e < ENUM; ++e) mx = fmaxf(mx, logit[e]);
        float p[ENUM]; float se = 0.f;
#pragma unroll
        for (int e = 0; e < ENUM; ++e) { p[e] = __expf(logit[e] - mx); se += p[e]; }
        float inv = 1.0f / se;
#pragma unroll
        for (int e = 0; e < ENUM; ++e) p[e] *= inv;
        int i0 = 0;
#pragma unroll
        for (int e = 1; e < ENUM; ++e) if (p[e] > p[i0]) i0 = e;
        int i1 = (i0 == 0) ? 1 : 0;
#pragma unroll
        for (int e = 0; e < ENUM; ++e) if (e != i0 && p[e] > p[i1]) i1 = e;
        tinfo[t] = i0 | (i1 << 4);
        wslot[(t << 1)] = p[i0];
        wslot[(t << 1) | 1] = p[i1];
    }
}

// ---- gate2: 8 blocks, wave-aggregated ballot compaction (round-5) --------
__global__ __launch_bounds__(256) void gate2_kernel(
    const int* __restrict__ tinfo, int* __restrict__ counts, int* __restrict__ toks)
{
    const int e = blockIdx.x;
    const int tid = threadIdx.x;
    const int lane = tid & 63;
    __shared__ int cnt;
    if (tid == 0) cnt = 0;
    __syncthreads();
    int* te = toks + e * TOK;
    for (int t = tid; t < TOK; t += 256) {
        int info = tinfo[t];
        ull m0 = __ballot((info & 15) == e);
        if (m0) {
            int base;
            if (lane == 0) base = atomicAdd(&cnt, __popcll(m0));
            base = __shfl(base, 0, 64);
            if ((m0 >> lane) & 1)
                te[base + __popcll(m0 & ((1ull << lane) - 1))] = (t << 1);
        }
        ull m1 = __ballot((info >> 4) == e);
        if (m1) {
            int base;
            if (lane == 0) base = atomicAdd(&cnt, __popcll(m1));
            base = __shfl(base, 0, 64);
            if ((m1 >> lane) & 1)
                te[base + __popcll(m1 & ((1ull << lane) - 1))] = (t << 1) | 1;
        }
    }
    __syncthreads();
    if (tid == 0) counts[e] = cnt;
}

// ---- up (round-5 exact): Hbuf[slot] = silu(x@w1g[e]) * (x@w1u[e]);
//      TM=128 TN=64, dbuf, 4 waves 2x2, XOR-swizzled LDS -------------------
__global__ __launch_bounds__(256, 4) void up_mfma(
    const ushort* __restrict__ xb, const ushort* __restrict__ BgP,
    const ushort* __restrict__ BuP, const int* __restrict__ counts,
    const int* __restrict__ toks, ushort* __restrict__ Hbuf)
{
    const int e = blockIdx.z;
    const int cnt = counts[e];
    const int m0 = blockIdx.y * 128;
    if (m0 >= cnt) return;
    const int nb = blockIdx.x;
    const int tid = threadIdx.x;
    const int w = tid >> 6;
    const int lane = tid & 63;
    const int q = lane >> 4;
    const int l15 = lane & 15;
    const int wr = w >> 1;   // 0..1 : m half (64 rows)
    const int wc = w & 1;    // 0..1 : n half (32 cols)

    __shared__ ushort As[2][128][32];
    __shared__ ushort Bgs[2][64][32];
    __shared__ ushort Bus[2][64][32];
    __shared__ int rowslot[128];

    if (tid < 128) rowslot[tid] = (m0 + tid < cnt) ? toks[e * TOK + m0 + tid] : -1;
    __syncthreads();

    const int srow = w * 16 + (lane >> 2);
    const int clog = (((lane & 3) + 4 - ((srow >> 1) & 3)) & 3) * 8;
    const int as0 = rowslot[srow];
    const int as1 = rowslot[srow + 64];
    const ushort* agp0 = xb + (size_t)(as0 < 0 ? 0 : (as0 >> 1)) * DDIM + clog;
    const ushort* agp1 = xb + (size_t)(as1 < 0 ? 0 : (as1 >> 1)) * DDIM + clog;
    const size_t tb = (size_t)(e * UP_NB + nb) * UP_KS * 2048;
    const ushort* bgp = BgP + tb + srow * 32 + clog;
    const ushort* bup = BuP + tb + srow * 32 + clog;

    const int coff = ((q + (l15 >> 1)) & 3) * 8;

    f32x4 accg[4][2], accu[4][2];
#pragma unroll
    for (int i = 0; i < 4; ++i)
#pragma unroll
        for (int j = 0; j < 2; ++j) { accg[i][j] = (f32x4)0.f; accu[i][j] = (f32x4)0.f; }

#define UP_PREFETCH(KSV, B)                                        \
    {                                                              \
        gl2lds16(agp0 + (KSV) * 32, &As[B][w * 16][0]);            \
        gl2lds16(agp1 + (KSV) * 32, &As[B][64 + w * 16][0]);       \
        gl2lds16(bgp + (size_t)(KSV) * 2048, &Bgs[B][w * 16][0]);  \
        gl2lds16(bup + (size_t)(KSV) * 2048, &Bus[B][w * 16][0]);  \
    }

    UP_PREFETCH(0, 0);
    __syncthreads();

    for (int ks = 0; ks < UP_KS; ++ks) {
        const int cur = ks & 1;
        const int nxt = cur ^ 1;
        if (ks + 1 < UP_KS) UP_PREFETCH(ks + 1, nxt);

        bf16x8 a[4], bg[2], bu[2];
#pragma unroll
        for (int mi = 0; mi < 4; ++mi)
            a[mi] = *(const bf16x8*)&As[cur][wr * 64 + mi * 16 + l15][coff];
#pragma unroll
        for (int ni = 0; ni < 2; ++ni) {
            bg[ni] = *(const bf16x8*)&Bgs[cur][wc * 32 + ni * 16 + l15][coff];
            bu[ni] = *(const bf16x8*)&Bus[cur][wc * 32 + ni * 16 + l15][coff];
        }
#pragma unroll
        for (int mi = 0; mi < 4; ++mi)
#pragma unroll
            for (int ni = 0; ni < 2; ++ni) {
                accg[mi][ni] = __builtin_amdgcn_mfma_f32_16x16x32_bf16(a[mi], bg[ni], accg[mi][ni], 0, 0, 0);
                accu[mi][ni] = __builtin_amdgcn_mfma_f32_16x16x32_bf16(a[mi], bu[ni], accu[mi][ni], 0, 0, 0);
            }
        __syncthreads();   // drains prefetch vmem + protects buffer swap
    }
#undef UP_PREFETCH

#pragma unroll
    for (int mi = 0; mi < 4; ++mi) {
#pragma unroll
        for (int r = 0; r < 4; ++r) {
            int ml = wr * 64 + mi * 16 + q * 4 + r;
            int slot = rowslot[ml];
            if (slot < 0) continue;
            ushort* hrow = Hbuf + (size_t)slot * HDIM + nb * 64 + wc * 32 + l15;
#pragma unroll
            for (int ni = 0; ni < 2; ++ni)
                hrow[ni * 16] = cvt_bf16(silu_f(accg[mi][ni][r]) * accu[mi][ni][r]);
        }
    }
}

// ---- down (round-5 exact): Ybuf partials = Hbuf[slot] @ w2[e];
//      TM=128 TN=128, K-split 2, dbuf, swizzled ----------------------------
__global__ __launch_bounds__(256, 4) void down_mfma(
    const ushort* __restrict__ Hbuf, const ushort* __restrict__ W2P,
    const int* __restrict__ counts, const int* __restrict__ toks,
    float* __restrict__ Ybuf)
{
    const int z = blockIdx.z;           // 0..15: expert*2 + K-half
    const int e = z >> 1;
    const int kh = z & 1;
    const int cnt = counts[e];
    const int m0 = blockIdx.y * 128;
    if (m0 >= cnt) return;
    const int nb = blockIdx.x;          // 0..7, 128-wide N blocks
    const int tid = threadIdx.x;
    const int w = tid >> 6;
    const int lane = tid & 63;
    const int q = lane >> 4;
    const int l15 = lane & 15;
    const int wr = w >> 1;
    const int wc = w & 1;

    __shared__ ushort As[2][128][32];
    __shared__ ushort Bs[2][128][32];
    __shared__ int rowslot[128];

    if (tid < 128) rowslot[tid] = (m0 + tid < cnt) ? toks[e * TOK + m0 + tid] : -1;
    __syncthreads();

    const int srow = w * 16 + (lane >> 2);
    const int clog = (((lane & 3) + 4 - ((srow >> 1) & 3)) & 3) * 8;
    const int as0 = rowslot[srow];
    const int as1 = rowslot[srow + 64];
    const ushort* agp0 = Hbuf + (size_t)(as0 < 0 ? 0 : as0) * HDIM + kh * (DN_KH * 32) + clog;
    const ushort* agp1 = Hbuf + (size_t)(as1 < 0 ? 0 : as1) * HDIM + kh * (DN_KH * 32) + clog;
    const int nb2 = nb * 2;
    const ushort* bp0 = W2P + ((size_t)(e * DN_NB + nb2) * DN_KS + kh * DN_KH) * 2048 + srow * 32 + clog;
    const ushort* bp1 = W2P + ((size_t)(e * DN_NB + nb2 + 1) * DN_KS + kh * DN_KH) * 2048 + srow * 32 + clog;

    const int coff = ((q + (l15 >> 1)) & 3) * 8;

    f32x4 acc[4][4];
#pragma unroll
    for (int i = 0; i < 4; ++i)
#pragma unroll
        for (int j = 0; j < 4; ++j) acc[i][j] = (f32x4)0.f;

#define DN_PREFETCH(KSV, B)                                           \
    {                                                                 \
        gl2lds16(agp0 + (KSV) * 32, &As[B][w * 16][0]);               \
        gl2lds16(agp1 + (KSV) * 32, &As[B][64 + w * 16][0]);          \
        gl2lds16(bp0 + (size_t)(KSV) * 2048, &Bs[B][w * 16][0]);      \
        gl2lds16(bp1 + (size_t)(KSV) * 2048, &Bs[B][64 + w * 16][0]); \
    }

    DN_PREFETCH(0, 0);
    __syncthreads();

    for (int ks = 0; ks < DN_KH; ++ks) {
        const int cur = ks & 1;
        const int nxt = cur ^ 1;
        if (ks + 1 < DN_KH) DN_PREFETCH(ks + 1, nxt);

        bf16x8 a[4], b[4];
#pragma unroll
        for (int mi = 0; mi < 4; ++mi)
            a[mi] = *(const bf16x8*)&As[cur][wr * 64 + mi * 16 + l15][coff];
#pragma unroll
        for (int ni = 0; ni < 4; ++ni)
            b[ni] = *(const bf16x8*)&Bs[cur][wc * 64 + ni * 16 + l15][coff];
#pragma unroll
        for (int mi = 0; mi < 4; ++mi)
#pragma unroll
            for (int ni = 0; ni < 4; ++ni)
                acc[mi][ni] = __builtin_amdgcn_mfma_f32_16x16x32_bf16(a[mi], b[ni], acc[mi][ni], 0, 0, 0);
        __syncthreads();
    }
#undef DN_PREFETCH

    float* Yp = Ybuf + (size_t)kh * NSLOT * DDIM;
#pragma unroll
    for (int mi = 0; mi < 4; ++mi) {
#pragma unroll
        for (int r = 0; r < 4; ++r) {
            int ml = wr * 64 + mi * 16 + q * 4 + r;
            int slot = rowslot[ml];
            if (slot < 0) continue;
            float* yr = Yp + (size_t)slot * DDIM + nb * 128 + wc * 64 + l15;
#pragma unroll
            for (int ni = 0; ni < 4; ++ni)
                yr[ni * 16] = acc[mi][ni][r];
        }
    }
}

// ---- combine: y[t] = w0*(Y0[2t]+Y1[2t]) + w1*(Y0[2t+1]+Y1[2t+1]) ---------
__global__ __launch_bounds__(256) void combine_kernel(
    const float* __restrict__ Ybuf, const float* __restrict__ wslot,
    float* __restrict__ y)
{
    const int t = blockIdx.x;
    const int j = threadIdx.x * 4;
    const float w0 = wslot[2 * t];
    const float w1 = wslot[2 * t + 1];
    const float* y00 = Ybuf + ((size_t)2 * t) * DDIM + j;
    const float* y01 = Ybuf + ((size_t)2 * t + 1) * DDIM + j;
    const float* y10 = y00 + (size_t)NSLOT * DDIM;
    const float* y11 = y01 + (size_t)NSLOT * DDIM;
    float4 a0 = *(const float4*)y00;
    float4 b0 = *(const float4*)y01;
    float4 a1 = *(const float4*)y10;
    float4 b1 = *(const float4*)y11;
    float4 o;
    o.x = w0 * (a0.x + a1.x) + w1 * (b0.x + b1.x);
    o.y = w0 * (a0.y + a1.y) + w1 * (b0.y + b1.y);
    o.z = w0 * (a0.z + a1.z) + w1 * (b0.z + b1.z);
    o.w = w0 * (a0.w + a1.w) + w1 * (b0.w + b1.w);
    *(float4*)(y + (size_t)t * DDIM + j) = o;
}

extern "C" void kernel_launch(void* const* d_in, const int* in_sizes, int n_in,
                              void* d_out, int out_size, void* d_ws, size_t ws_size,
                              hipStream_t stream) {
    const float* x   = (const float*)d_in[0];
    const float* gw  = (const float*)d_in[1];
    const float* w1g = (const float*)d_in[2];
    const float* w1u = (const float*)d_in[3];
    const float* w2  = (const float*)d_in[4];
    float* y = (float*)d_out;
    char* ws = (char*)d_ws;

    // workspace layout (Ybuf [2 K-halves] aliases BgP/BuP region — dead after up)
    size_t off = 0;
    int*    counts = (int*)(ws + off);   off += 256;
    int*    toks   = (int*)(ws + off);   off += (size_t)ENUM * TOK * 4;   // 64 KB
    float*  wslot  = (float*)(ws + off); off += (size_t)NSLOT * 4;        // 16 KB
    int*    tinfo  = (int*)(ws + off);   off += (size_t)TOK * 4;          // 8 KB
    off = (off + 255) & ~(size_t)255;
    ushort* xb     = (ushort*)(ws + off); off += (size_t)TOK * DDIM * 2;  // 4 MB
    size_t regA = off;                                                    // 46 MB region
    ushort* BgP  = (ushort*)(ws + regA);
    ushort* BuP  = (ushort*)(ws + regA + (size_t)ENUM * DDIM * HDIM * 2);
    float*  Ybuf = (float*)(ws + regA);                                   // 33.6 MB alias
    off = regA + (size_t)2 * ENUM * DDIM * HDIM * 2;
    ushort* W2P  = (ushort*)(ws + off);  off += (size_t)ENUM * HDIM * DDIM * 2; // 23 MB
    ushort* Hbuf = (ushort*)(ws + off);                                         // 11.5 MB

    tcast_gate_kernel<<<TC_ALL_BLK + GATE_BLK, 256, 0, stream>>>(
        w1g, w1u, w2, BgP, BuP, W2P, x, gw, tinfo, wslot, xb);
    gate2_kernel<<<ENUM, 256, 0, stream>>>(tinfo, counts, toks);

    up_mfma<<<dim3(UP_NB, TOK / 128, ENUM), 256, 0, stream>>>(xb, BgP, BuP, counts, toks, Hbuf);
    down_mfma<<<dim3(DDIM / 128, TOK / 128, 16), 256, 0, stream>>>(Hbuf, W2P, counts, toks, Ybuf);
    combine_kernel<<<TOK, 256, 0, stream>>>(Ybuf, wslot, y);
}